// Round 5
// baseline (897.065 us; speedup 1.0000x reference)
//
#include <hip/hip_runtime.h>
#include <hip/hip_cooperative_groups.h>
#include <cstdint>
#include <cstddef>

namespace cg = cooperative_groups;

// ---------------- problem constants ----------------
#define E_EDGES     524288
#define N_TOT       16384      // total nodes (8 graphs x 2048)
#define HID         64
#define B_GR        8
#define KTOT        131072     // NPG*HID, FC1 inner dim
#define NJ          2048       // FC1 output width
#define MAXN        15

// mega-kernel grid
#define MB          512        // blocks
#define MT          256        // threads/block

// FC1 tiling: 256 blocks, each streams a contiguous 4 MB slab (512 rows)
#define FKC         512
#define FNB         256        // KTOT/FKC

// ---------------- workspace layout (bytes) ----------------
// [0, 0x70000) zeroed with ONE memset: degi | cursor | aggx | zacc
#define OFF_DEGI    0x0u         // 64 KB (16384 int)
#define OFF_CURSOR  0x10000u     // 64 KB
#define OFF_AGGX    0x20000u     // 256 KB (16384 x 4 f32)
#define OFF_ZACC    0x60000u     // 64 KB (8 x 2048 f32)
#define OFF_DIS     0x70000u     // 64 KB
#define OFF_ROWPTR  0x80000u     // 64 KB + 4
#define OFF_BLKSUM  0x98000u     // 256 B (64 int)
#define OFF_CSR     0xA0000u     // 4 MB (524288 int2)
#define OFF_H1      0x4A0000u    // 4 MB
#define OFF_AGG2    0x8A0000u    // 4 MB
#define OFF_H2      0xCA0000u    // 4 MB -> ends 0x10A0000 (~17.4 MB)

__device__ __forceinline__ float selu_f(float x) {
    const float scale = 1.0507009873554805f;
    const float alpha = 1.6732632423543772f;
    return x > 0.0f ? scale * x : scale * alpha * expm1f(x);
}

// ================= fused GCN phase (cooperative) =================
__launch_bounds__(MT, 2)
__global__ void gcn_mega_kernel(const int* __restrict__ src, const int* __restrict__ dst,
                                const float* __restrict__ x,
                                const float* __restrict__ W1, const float* __restrict__ b1,
                                const float* __restrict__ W2, const float* __restrict__ b2,
                                int* __restrict__ degi, int* __restrict__ cursor,
                                float* __restrict__ aggx, float* __restrict__ dis,
                                int* __restrict__ rowptr, int* __restrict__ blksum,
                                int2* __restrict__ csr, float* __restrict__ h1,
                                float* __restrict__ agg2, float* __restrict__ h2) {
    cg::grid_group grid = cg::this_grid();
    const int bid = blockIdx.x;
    const int tid = threadIdx.x;
    __shared__ float w2s[HID * HID];   // 16 KB (used in S6; scratch for scans)
    int* scanbuf = (int*)w2s;          // 256 ints, disjoint-in-time from S6 use

    // ---- S1: in-degree over dst ----
    for (int e = bid * MT + tid; e < E_EDGES; e += MB * MT)
        atomicAdd(&degi[dst[e]], 1);
    grid.sync();

    // ---- S2a: 64 blocks compute block sums of degi (256 elems each) ----
    if (bid < 64) {
        int dg = degi[bid * 256 + tid];
        scanbuf[tid] = dg;
        __syncthreads();
        for (int s = 128; s > 0; s >>= 1) {
            if (tid < s) scanbuf[tid] += scanbuf[tid + s];
            __syncthreads();
        }
        if (tid == 0) blksum[bid] = scanbuf[0];
    }
    grid.sync();

    // ---- S2b: serial exclusive scan of 64 block sums ----
    if (bid == 0 && tid == 0) {
        int run = 0;
        for (int i = 0; i < 64; ++i) { int t = blksum[i]; blksum[i] = run; run += t; }
        rowptr[N_TOT] = run;   // == E_EDGES
    }
    grid.sync();

    // ---- S2c: block-local inclusive scan -> rowptr, dis ----
    if (bid < 64) {
        int i = bid * 256 + tid;
        int dg = degi[i];
        scanbuf[tid] = dg;
        __syncthreads();
        for (int s = 1; s < 256; s <<= 1) {
            int v = (tid >= s) ? scanbuf[tid - s] : 0;
            __syncthreads();
            scanbuf[tid] += v;
            __syncthreads();
        }
        rowptr[i] = blksum[bid] + scanbuf[tid] - dg;
        dis[i] = rsqrtf((float)(dg + 1));
    }
    grid.sync();

    // ---- S3: CSR scatter (col + dis[src]) + layer-1 aggregation atomics ----
    for (int e = bid * MT + tid; e < E_EDGES; e += MB * MT) {
        int s = src[e], d = dst[e];
        float dss = dis[s];
        float nrm = dss * dis[d];
        int pos = atomicAdd(&cursor[d], 1);
        int2 cw; cw.x = s; cw.y = __float_as_int(dss);
        csr[rowptr[d] + pos] = cw;
        const float4 xv = *reinterpret_cast<const float4*>(x + (size_t)s * 4);
        float* o = aggx + (size_t)d * 4;
        atomicAdd(o + 0, xv.x * nrm);
        atomicAdd(o + 1, xv.y * nrm);
        atomicAdd(o + 2, xv.z * nrm);
        atomicAdd(o + 3, xv.w * nrm);
    }
    grid.sync();

    // ---- S4: h1 = selu( (aggx + x*dis^2) @ W1 + b1 ) ----
    for (int t = bid * MT + tid; t < N_TOT * HID; t += MB * MT) {
        int i = t >> 6, oc = t & 63;
        float ds = dis[i];
        float d2 = ds * ds;
        const float4 a  = *reinterpret_cast<const float4*>(aggx + (size_t)i * 4);
        const float4 xv = *reinterpret_cast<const float4*>(x    + (size_t)i * 4);
        float v = b1[oc];
        v = fmaf(a.x + xv.x * d2, W1[       oc], v);
        v = fmaf(a.y + xv.y * d2, W1[ 64 +  oc], v);
        v = fmaf(a.z + xv.z * d2, W1[128 +  oc], v);
        v = fmaf(a.w + xv.w * d2, W1[192 +  oc], v);
        h1[t] = selu_f(v);
    }
    grid.sync();

    // ---- S5: layer-2 aggregation via CSR gather (wave per node) ----
    {
        int gwave = bid * (MT / 64) + (tid >> 6);   // 0..2047
        int c = tid & 63;
        for (int node = gwave; node < N_TOT; node += MB * (MT / 64)) {
            int beg = rowptr[node], end = rowptr[node + 1];
            float acc = 0.f;
            int i = beg;
            for (; i + 3 < end; i += 4) {
                int2 a = csr[i];
                int2 b = csr[i + 1];
                int2 cc = csr[i + 2];
                int2 dd = csr[i + 3];
                acc = fmaf(h1[(size_t)a.x  * HID + c], __int_as_float(a.y),  acc);
                acc = fmaf(h1[(size_t)b.x  * HID + c], __int_as_float(b.y),  acc);
                acc = fmaf(h1[(size_t)cc.x * HID + c], __int_as_float(cc.y), acc);
                acc = fmaf(h1[(size_t)dd.x * HID + c], __int_as_float(dd.y), acc);
            }
            for (; i < end; ++i) {
                int2 a = csr[i];
                acc = fmaf(h1[(size_t)a.x * HID + c], __int_as_float(a.y), acc);
            }
            agg2[(size_t)node * HID + c] = acc * dis[node];
        }
    }
    grid.sync();

    // ---- S6: h2 = selu( (agg2 + h1*dis^2) @ W2 + b2 ), W2 in LDS, shfl bcast ----
    __syncthreads();   // all waves done using scanbuf alias before w2s store
    for (int idx = tid; idx < HID * HID; idx += MT) w2s[idx] = W2[idx];
    __syncthreads();
    {
        int oc = tid & 63;
        int wv = tid >> 6;            // 0..3
        for (int g = bid; g < N_TOT / 4; g += MB) {
            int node = g * 4 + wv;
            float ds = dis[node];
            size_t base = (size_t)node * HID + oc;
            float inv = agg2[base] + h1[base] * ds * ds;
            float acc = b2[oc];
            #pragma unroll
            for (int c = 0; c < HID; ++c)
                acc = fmaf(__shfl(inv, c, 64), w2s[c * HID + oc], acc);
            h2[base] = selu_f(acc);
        }
    }
}

// ================= FC1: contiguous 4 MB slab per block, atomic z =================
__launch_bounds__(512, 2)
__global__ void fc1_kernel(const float* __restrict__ h2, const float* __restrict__ Wf1,
                           float* __restrict__ zacc) {
    __shared__ float hch[B_GR * FKC];     // 16 KB, [b][kk]
    const int k0 = blockIdx.x * FKC;
    for (int idx = threadIdx.x; idx < B_GR * FKC; idx += 512) {
        int b = idx >> 9;                 // FKC = 512
        int kk = idx & (FKC - 1);
        hch[idx] = h2[(size_t)b * KTOT + k0 + kk];
    }
    __syncthreads();
    float4 acc[B_GR];
    #pragma unroll
    for (int b = 0; b < B_GR; ++b) acc[b] = make_float4(0.f, 0.f, 0.f, 0.f);
    const int j = threadIdx.x * 4;
    const float* wp = Wf1 + (size_t)k0 * NJ + j;
    #pragma unroll 4
    for (int kk = 0; kk < FKC; ++kk) {
        float4 w = *reinterpret_cast<const float4*>(wp);
        wp += NJ;
        #pragma unroll
        for (int b = 0; b < B_GR; ++b) {
            float hv = hch[b * FKC + kk];
            acc[b].x = fmaf(w.x, hv, acc[b].x);
            acc[b].y = fmaf(w.y, hv, acc[b].y);
            acc[b].z = fmaf(w.z, hv, acc[b].z);
            acc[b].w = fmaf(w.w, hv, acc[b].w);
        }
    }
    #pragma unroll
    for (int b = 0; b < B_GR; ++b) {
        float* zp = zacc + (size_t)b * NJ + j;
        atomicAdd(zp + 0, acc[b].x);
        atomicAdd(zp + 1, acc[b].y);
        atomicAdd(zp + 2, acc[b].z);
        atomicAdd(zp + 3, acc[b].w);
    }
}

// ---- FC2 (+ FC1 bias & selu finalize): out[b][m] ----
__global__ void fc2_kernel(const float* __restrict__ zacc, const float* __restrict__ bf1,
                           const float* __restrict__ Wf2, const float* __restrict__ bf2,
                           float* __restrict__ out) {
    int b = blockIdx.x;
    int t = threadIdx.x;  // 64
    float acc[MAXN];
    #pragma unroll
    for (int m = 0; m < MAXN; ++m) acc[m] = 0.f;
    for (int j = t; j < NJ; j += 64) {
        float zv = selu_f(zacc[(size_t)b * NJ + j] + bf1[j]);
        const float* wr = Wf2 + (size_t)j * MAXN;
        #pragma unroll
        for (int m = 0; m < MAXN; ++m) acc[m] = fmaf(zv, wr[m], acc[m]);
    }
    #pragma unroll
    for (int m = 0; m < MAXN; ++m) {
        float v = acc[m];
        for (int off = 32; off > 0; off >>= 1) v += __shfl_down(v, off, 64);
        if (t == 0) out[b * MAXN + m] = v + bf2[m];
    }
}

extern "C" void kernel_launch(void* const* d_in, const int* in_sizes, int n_in,
                              void* d_out, int out_size, void* d_ws, size_t ws_size,
                              hipStream_t stream) {
    const float* x    = (const float*)d_in[0];
    const int*   ei   = (const int*)d_in[1];      // int32 (JAX x64 disabled)
    const float* W1   = (const float*)d_in[2];
    const float* b1   = (const float*)d_in[3];
    const float* W2   = (const float*)d_in[4];
    const float* b2   = (const float*)d_in[5];
    const float* Wf1  = (const float*)d_in[6];
    const float* bf1  = (const float*)d_in[7];
    const float* Wf2  = (const float*)d_in[8];
    const float* bf2  = (const float*)d_in[9];
    float* out = (float*)d_out;

    const int* src = ei;
    const int* dst = ei + E_EDGES;

    char* ws = (char*)d_ws;
    int*   degi   = (int*)  (ws + OFF_DEGI);
    int*   cursor = (int*)  (ws + OFF_CURSOR);
    float* aggx   = (float*)(ws + OFF_AGGX);
    float* zacc   = (float*)(ws + OFF_ZACC);
    float* dis    = (float*)(ws + OFF_DIS);
    int*   rowptr = (int*)  (ws + OFF_ROWPTR);
    int*   blksum = (int*)  (ws + OFF_BLKSUM);
    int2*  csr    = (int2*) (ws + OFF_CSR);
    float* h1     = (float*)(ws + OFF_H1);
    float* agg2   = (float*)(ws + OFF_AGG2);
    float* h2     = (float*)(ws + OFF_H2);

    // single contiguous zero: degi | cursor | aggx | zacc
    hipMemsetAsync(ws, 0, 0x70000, stream);

    void* margs[] = { (void*)&src, (void*)&dst, (void*)&x,
                      (void*)&W1, (void*)&b1, (void*)&W2, (void*)&b2,
                      (void*)&degi, (void*)&cursor, (void*)&aggx, (void*)&dis,
                      (void*)&rowptr, (void*)&blksum, (void*)&csr,
                      (void*)&h1, (void*)&agg2, (void*)&h2 };
    hipLaunchCooperativeKernel((void*)gcn_mega_kernel, dim3(MB), dim3(MT),
                               margs, 0, stream);

    fc1_kernel <<<FNB, 512, 0, stream>>>(h2, Wf1, zacc);
    fc2_kernel <<<B_GR, 64, 0, stream>>>(zacc, bf1, Wf2, bf2, out);
}

// Round 6
// 446.523 us; speedup vs baseline: 2.0090x; 2.0090x over previous
//
#include <hip/hip_runtime.h>
#include <cstdint>
#include <cstddef>

// ---------------- problem constants ----------------
#define E_EDGES     524288
#define N_TOT       16384      // total nodes (8 graphs x 2048)
#define HID         64
#define B_GR        8
#define KTOT        131072     // NPG*HID, FC1 inner dim
#define NJ          2048       // FC1 output width
#define MAXN        15

// FC1 tiling: one block = full 2048-wide row (512 thr x float4), KC rows
#define KC          256
#define NCHUNK      512        // KTOT/KC

// ---------------- workspace layout (bytes) ----------------
// [0, 0x60000) is zeroed with ONE memset: degi | cursor | aggx
#define OFF_DEGI    0x0u         // 64 KB (16384 int)
#define OFF_CURSOR  0x10000u     // 64 KB
#define OFF_AGGX    0x20000u     // 256 KB (16384 x 4 f32)
#define OFF_DIS     0x60000u     // 64 KB
#define OFF_ROWPTR  0x70000u     // 64 KB + 4 (padded to 128 KB)
#define OFF_CSR     0x90000u     // 4 MB (524288 int2)
#define OFF_H1      0x490000u    // 4 MB
#define OFF_H2      0x890000u    // 4 MB
#define OFF_TMP     0xC90000u    // 512 KB (8 x 16384 f32)
#define OFF_PART    0xD90000u    // 33.55 MB (512 x 8 x 2048 f32)

__device__ __forceinline__ float selu_f(float x) {
    const float scale = 1.0507009873554805f;
    const float alpha = 1.6732632423543772f;
    return x > 0.0f ? scale * x : scale * alpha * expm1f(x);
}

// ---- degree (in-degree over dst; +1 self-loop handled in dis) ----
__global__ void deg_kernel(const int* __restrict__ dst, int* __restrict__ degi) {
    int e = blockIdx.x * 256 + threadIdx.x;
    if (e < E_EDGES) atomicAdd(&degi[dst[e]], 1);
}

// ---- exclusive scan of degi -> rowptr, plus dis = rsqrt(deg+1) (1 block) ----
__global__ void scan_kernel(const int* __restrict__ degi, int* __restrict__ rowptr,
                            float* __restrict__ dis) {
    __shared__ int pref[257];
    __shared__ int sums[256];
    int t = threadIdx.x;
    int base = t * 64;
    int s = 0;
    for (int i = 0; i < 64; ++i) s += degi[base + i];
    sums[t] = s;
    __syncthreads();
    if (t == 0) {
        int run = 0;
        for (int i = 0; i < 256; ++i) { pref[i] = run; run += sums[i]; }
        pref[256] = run;
    }
    __syncthreads();
    int run = pref[t];
    for (int i = 0; i < 64; ++i) {
        int dg = degi[base + i];
        rowptr[base + i] = run; run += dg;
        dis[base + i] = rsqrtf((float)(dg + 1));
    }
    if (t == 255) rowptr[N_TOT] = pref[256];
}

// ---- fused: CSR scatter (col + weight) AND layer-1 aggregation atomics ----
__global__ void scatter_agg1_kernel(const int* __restrict__ src, const int* __restrict__ dst,
                                    const float* __restrict__ x, const float* __restrict__ dis,
                                    const int* __restrict__ rowptr, int* __restrict__ cursor,
                                    int2* __restrict__ csr, float* __restrict__ aggx) {
    int e = blockIdx.x * 256 + threadIdx.x;
    if (e >= E_EDGES) return;
    int s = src[e], d = dst[e];
    float dss = dis[s];
    float nrm = dss * dis[d];
    int pos = atomicAdd(&cursor[d], 1);
    int2 cw; cw.x = s; cw.y = __float_as_int(dss);
    csr[rowptr[d] + pos] = cw;
    const float4 xv = *reinterpret_cast<const float4*>(x + (size_t)s * 4);
    float* o = aggx + (size_t)d * 4;
    atomicAdd(o + 0, xv.x * nrm);
    atomicAdd(o + 1, xv.y * nrm);
    atomicAdd(o + 2, xv.z * nrm);
    atomicAdd(o + 3, xv.w * nrm);
}

// ---- h1 = selu( (aggx + x*dis^2) @ W1 + b1 ), thread per (node, oc) ----
__global__ void h1_kernel(const float* __restrict__ aggx, const float* __restrict__ x,
                          const float* __restrict__ dis, const float* __restrict__ W1,
                          const float* __restrict__ b1, float* __restrict__ h1) {
    int t = blockIdx.x * 256 + threadIdx.x;     // N_TOT*64 threads
    int i = t >> 6, oc = t & 63;
    float ds = dis[i];
    float d2 = ds * ds;
    const float4 a  = *reinterpret_cast<const float4*>(aggx + (size_t)i * 4);
    const float4 xv = *reinterpret_cast<const float4*>(x    + (size_t)i * 4);
    float v = b1[oc];
    v = fmaf(a.x + xv.x * d2, W1[       oc], v);
    v = fmaf(a.y + xv.y * d2, W1[ 64 +  oc], v);
    v = fmaf(a.z + xv.z * d2, W1[128 +  oc], v);
    v = fmaf(a.w + xv.w * d2, W1[192 +  oc], v);
    h1[t] = selu_f(v);
}

// ---- fused layer-2: CSR gather (agg2 in registers) + W2 matmul + selu ----
// wave per node (lane = channel); W2 staged in LDS once per block.
__launch_bounds__(256)
__global__ void agg2h2_kernel(const int* __restrict__ rowptr, const int2* __restrict__ csr,
                              const float* __restrict__ h1, const float* __restrict__ dis,
                              const float* __restrict__ W2, const float* __restrict__ b2,
                              float* __restrict__ h2) {
    __shared__ float w2s[HID * HID];      // 16 KB
    for (int idx = threadIdx.x; idx < HID * HID; idx += 256) w2s[idx] = W2[idx];
    __syncthreads();

    int node = blockIdx.x * 4 + (threadIdx.x >> 6);
    int c = threadIdx.x & 63;
    int beg = rowptr[node], end = rowptr[node + 1];
    float acc = 0.f;
    int i = beg;
    for (; i + 3 < end; i += 4) {
        int2 a = csr[i];
        int2 b = csr[i + 1];
        int2 cc = csr[i + 2];
        int2 dd = csr[i + 3];
        acc = fmaf(h1[(size_t)a.x  * HID + c], __int_as_float(a.y),  acc);
        acc = fmaf(h1[(size_t)b.x  * HID + c], __int_as_float(b.y),  acc);
        acc = fmaf(h1[(size_t)cc.x * HID + c], __int_as_float(cc.y), acc);
        acc = fmaf(h1[(size_t)dd.x * HID + c], __int_as_float(dd.y), acc);
    }
    for (; i < end; ++i) {
        int2 a = csr[i];
        acc = fmaf(h1[(size_t)a.x * HID + c], __int_as_float(a.y), acc);
    }
    float ds = dis[node];
    size_t base = (size_t)node * HID + c;
    float inv = acc * ds + h1[base] * ds * ds;   // agg2 + h1*dis^2, channel c

    // h2[node][oc=c] = selu( b2[oc] + sum_cc inv_cc * W2[cc][oc] )
    float o = b2[c];
    #pragma unroll
    for (int cc = 0; cc < HID; ++cc)
        o = fmaf(__shfl(inv, cc, 64), w2s[cc * HID + c], o);
    h2[base] = selu_f(o);
}

// ---- FC1: block = 512 thr x float4 = full 2048-wide row; KC contiguous rows.
// Each block streams a contiguous 2 MB slab of Wf1 exactly once.
__launch_bounds__(512, 4)
__global__ void fc1_kernel(const float* __restrict__ h2, const float* __restrict__ Wf1,
                           float* __restrict__ partials) {
    __shared__ float hch[B_GR * KC];      // 8 KB, [b][kk]
    const int chunk = blockIdx.x;         // 0..NCHUNK-1
    const int k0 = chunk * KC;
    for (int idx = threadIdx.x; idx < B_GR * KC; idx += 512) {
        int b = idx >> 8;                 // KC = 256
        int kk = idx & (KC - 1);
        hch[idx] = h2[(size_t)b * KTOT + k0 + kk];
    }
    __syncthreads();
    float4 acc[B_GR];
    #pragma unroll
    for (int b = 0; b < B_GR; ++b) acc[b] = make_float4(0.f, 0.f, 0.f, 0.f);
    const int j = threadIdx.x * 4;
    const float* wp = Wf1 + (size_t)k0 * NJ + j;
    #pragma unroll 4
    for (int kk = 0; kk < KC; ++kk) {
        float4 w = *reinterpret_cast<const float4*>(wp);
        wp += NJ;
        #pragma unroll
        for (int b = 0; b < B_GR; ++b) {
            float hv = hch[b * KC + kk];
            acc[b].x = fmaf(w.x, hv, acc[b].x);
            acc[b].y = fmaf(w.y, hv, acc[b].y);
            acc[b].z = fmaf(w.z, hv, acc[b].z);
            acc[b].w = fmaf(w.w, hv, acc[b].w);
        }
    }
    float* pp = partials + (size_t)chunk * (B_GR * NJ) + j;
    #pragma unroll
    for (int b = 0; b < B_GR; ++b)
        *reinterpret_cast<float4*>(pp + (size_t)b * NJ) = acc[b];
}

// ---- reduce stage 1: 512 chunks -> 8 group-partials ----
__global__ void fc1_reduce1_kernel(const float* __restrict__ partials, float* __restrict__ tmp) {
    int idx = blockIdx.x * 256 + threadIdx.x;   // 0..16383
    int g = blockIdx.y;                         // 0..7  (64 chunks each)
    float s = 0.f;
    const float* p = partials + (size_t)(g * 64) * (B_GR * NJ) + idx;
    #pragma unroll 8
    for (int c = 0; c < 64; ++c) { s += *p; p += B_GR * NJ; }
    tmp[(size_t)g * (B_GR * NJ) + idx] = s;
}

// ---- FC2 (+ final reduce + FC1 bias & selu): out[b][m] ----
__global__ void fc2_kernel(const float* __restrict__ tmp, const float* __restrict__ bf1,
                           const float* __restrict__ Wf2, const float* __restrict__ bf2,
                           float* __restrict__ out) {
    int b = blockIdx.x;
    int t = threadIdx.x;  // 64
    float acc[MAXN];
    #pragma unroll
    for (int m = 0; m < MAXN; ++m) acc[m] = 0.f;
    for (int j = t; j < NJ; j += 64) {
        size_t o = (size_t)b * NJ + j;
        float s = 0.f;
        #pragma unroll
        for (int g = 0; g < 8; ++g) s += tmp[(size_t)g * (B_GR * NJ) + o];
        float zv = selu_f(s + bf1[j]);
        const float* wr = Wf2 + (size_t)j * MAXN;
        #pragma unroll
        for (int m = 0; m < MAXN; ++m) acc[m] = fmaf(zv, wr[m], acc[m]);
    }
    #pragma unroll
    for (int m = 0; m < MAXN; ++m) {
        float v = acc[m];
        for (int off = 32; off > 0; off >>= 1) v += __shfl_down(v, off, 64);
        if (t == 0) out[b * MAXN + m] = v + bf2[m];
    }
}

extern "C" void kernel_launch(void* const* d_in, const int* in_sizes, int n_in,
                              void* d_out, int out_size, void* d_ws, size_t ws_size,
                              hipStream_t stream) {
    const float* x    = (const float*)d_in[0];
    const int*   ei   = (const int*)d_in[1];      // int32 (JAX x64 disabled)
    const float* W1   = (const float*)d_in[2];
    const float* b1   = (const float*)d_in[3];
    const float* W2   = (const float*)d_in[4];
    const float* b2   = (const float*)d_in[5];
    const float* Wf1  = (const float*)d_in[6];
    const float* bf1  = (const float*)d_in[7];
    const float* Wf2  = (const float*)d_in[8];
    const float* bf2  = (const float*)d_in[9];
    float* out = (float*)d_out;

    const int* src = ei;
    const int* dst = ei + E_EDGES;

    char* ws = (char*)d_ws;
    int*   degi   = (int*)  (ws + OFF_DEGI);
    int*   cursor = (int*)  (ws + OFF_CURSOR);
    float* aggx   = (float*)(ws + OFF_AGGX);
    float* dis    = (float*)(ws + OFF_DIS);
    int*   rowptr = (int*)  (ws + OFF_ROWPTR);
    int2*  csr    = (int2*) (ws + OFF_CSR);
    float* h1     = (float*)(ws + OFF_H1);
    float* h2     = (float*)(ws + OFF_H2);
    float* tmp    = (float*)(ws + OFF_TMP);
    float* parts  = (float*)(ws + OFF_PART);

    // single contiguous zero: degi | cursor | aggx
    hipMemsetAsync(ws, 0, 0x60000, stream);

    deg_kernel <<<E_EDGES / 256, 256, 0, stream>>>(dst, degi);
    scan_kernel<<<1, 256, 0, stream>>>(degi, rowptr, dis);
    scatter_agg1_kernel<<<E_EDGES / 256, 256, 0, stream>>>(src, dst, x, dis, rowptr,
                                                           cursor, csr, aggx);
    h1_kernel  <<<(N_TOT * HID) / 256, 256, 0, stream>>>(aggx, x, dis, W1, b1, h1);
    agg2h2_kernel<<<N_TOT / 4, 256, 0, stream>>>(rowptr, csr, h1, dis, W2, b2, h2);
    fc1_kernel <<<NCHUNK, 512, 0, stream>>>(h2, Wf1, parts);
    fc1_reduce1_kernel<<<dim3(64, 8), 256, 0, stream>>>(parts, tmp);
    fc2_kernel <<<B_GR, 64, 0, stream>>>(tmp, bf1, Wf2, bf2, out);
}

// Round 7
// 372.529 us; speedup vs baseline: 2.4080x; 1.1986x over previous
//
#include <hip/hip_runtime.h>
#include <cstdint>
#include <cstddef>

// ---------------- problem constants ----------------
#define E_EDGES     524288
#define N_TOT       16384      // total nodes (8 graphs x 2048)
#define HID         64
#define B_GR        8
#define KTOT        131072     // NPG*HID, FC1 inner dim
#define NJ          2048       // FC1 output width
#define MAXN        15

// FC1 tiling: one block = full 2048-wide row (512 thr x float4), KC rows
#define KC          256
#define NCHUNK      512        // KTOT/KC

// ---------------- workspace layout (bytes) ----------------
// [0, 0x20000) zeroed with ONE memset: degi | cursor
#define OFF_DEGI    0x0u         // 64 KB (16384 int)
#define OFF_CURSOR  0x10000u     // 64 KB
#define OFF_DIS     0x20000u     // 64 KB
#define OFF_ROWPTR  0x30000u     // 64 KB + 4 (padded to 128 KB)
#define OFF_CSR     0x50000u     // 4 MB (524288 int2)
#define OFF_H1      0x450000u    // 4 MB
#define OFF_H2      0x850000u    // 4 MB
#define OFF_TMP     0xC50000u    // 512 KB (8 x 16384 f32)
#define OFF_PART    0xD00000u    // 33.55 MB (512 x 8 x 2048 f32)

__device__ __forceinline__ float selu_f(float x) {
    const float scale = 1.0507009873554805f;
    const float alpha = 1.6732632423543772f;
    return x > 0.0f ? scale * x : scale * alpha * expm1f(x);
}

// ---- degree (in-degree over dst; +1 self-loop handled in dis) ----
__global__ void deg_kernel(const int* __restrict__ dst, int* __restrict__ degi) {
    int e = blockIdx.x * 256 + threadIdx.x;
    if (e < E_EDGES) atomicAdd(&degi[dst[e]], 1);
}

// ---- parallel exclusive scan of degi -> rowptr, plus dis = rsqrt(deg+1) ----
// one block, 1024 threads = 16 waves; 16 elems/thread
__launch_bounds__(1024)
__global__ void scan_kernel(const int* __restrict__ degi, int* __restrict__ rowptr,
                            float* __restrict__ dis) {
    __shared__ int wsum[16];
    int t = threadIdx.x;
    int lane = t & 63, wv = t >> 6;
    int base = t * 16;
    int v[16];
    int s = 0;
    #pragma unroll
    for (int i = 0; i < 16; ++i) { v[i] = degi[base + i]; s += v[i]; }
    // inclusive wave scan of thread sums
    int sc = s;
    #pragma unroll
    for (int off = 1; off < 64; off <<= 1) {
        int n = __shfl_up(sc, off, 64);
        if (lane >= off) sc += n;
    }
    if (lane == 63) wsum[wv] = sc;
    __syncthreads();
    if (wv == 0 && lane < 16) {
        int ws = wsum[lane];
        int scw = ws;
        #pragma unroll
        for (int off = 1; off < 16; off <<= 1) {
            int n = __shfl_up(scw, off, 64);
            if (lane >= off) scw += n;
        }
        wsum[lane] = scw - ws;   // exclusive wave offset
    }
    __syncthreads();
    int run = wsum[wv] + (sc - s);   // exclusive prefix for this thread's chunk
    #pragma unroll
    for (int i = 0; i < 16; ++i) {
        rowptr[base + i] = run; run += v[i];
        dis[base + i] = rsqrtf((float)(v[i] + 1));
    }
    if (t == 0) rowptr[N_TOT] = E_EDGES;
}

// ---- CSR build only: cursor RMW + int2 store (no float atomics) ----
__global__ void scatter_kernel(const int* __restrict__ src, const int* __restrict__ dst,
                               const float* __restrict__ dis,
                               const int* __restrict__ rowptr, int* __restrict__ cursor,
                               int2* __restrict__ csr) {
    int e = blockIdx.x * 256 + threadIdx.x;
    if (e >= E_EDGES) return;
    int s = src[e], d = dst[e];
    int pos = atomicAdd(&cursor[d], 1);
    int2 cw; cw.x = s; cw.y = __float_as_int(dis[s]);
    csr[rowptr[d] + pos] = cw;
}

// ---- layer 1 fused: gather over CSR with on-the-fly x@W1 (linearity) ----
// h1[d][c] = selu( dis[d]*sum_s dis[s]*(x[s]@W1)_c + dis[d]^2*(x[d]@W1)_c + b1[c] )
__launch_bounds__(256)
__global__ void gather1_kernel(const int* __restrict__ rowptr, const int2* __restrict__ csr,
                               const float* __restrict__ x, const float* __restrict__ dis,
                               const float* __restrict__ W1, const float* __restrict__ b1,
                               float* __restrict__ h1) {
    int node = blockIdx.x * 4 + (threadIdx.x >> 6);
    int c = threadIdx.x & 63;
    float w0 = W1[c], w1 = W1[64 + c], w2 = W1[128 + c], w3 = W1[192 + c];
    int beg = rowptr[node], end = rowptr[node + 1];
    float acc = 0.f;
    int i = beg;
    for (; i + 1 < end; i += 2) {
        int2 a = csr[i];
        int2 b = csr[i + 1];
        const float4 xa = *reinterpret_cast<const float4*>(x + (size_t)a.x * 4);
        const float4 xb = *reinterpret_cast<const float4*>(x + (size_t)b.x * 4);
        float xwa = fmaf(xa.x, w0, fmaf(xa.y, w1, fmaf(xa.z, w2, xa.w * w3)));
        float xwb = fmaf(xb.x, w0, fmaf(xb.y, w1, fmaf(xb.z, w2, xb.w * w3)));
        acc = fmaf(xwa, __int_as_float(a.y), acc);
        acc = fmaf(xwb, __int_as_float(b.y), acc);
    }
    if (i < end) {
        int2 a = csr[i];
        const float4 xa = *reinterpret_cast<const float4*>(x + (size_t)a.x * 4);
        float xwa = fmaf(xa.x, w0, fmaf(xa.y, w1, fmaf(xa.z, w2, xa.w * w3)));
        acc = fmaf(xwa, __int_as_float(a.y), acc);
    }
    float ds = dis[node];
    const float4 xd = *reinterpret_cast<const float4*>(x + (size_t)node * 4);
    float xwd = fmaf(xd.x, w0, fmaf(xd.y, w1, fmaf(xd.z, w2, xd.w * w3)));
    float val = fmaf(acc, ds, xwd * ds * ds) + b1[c];
    h1[(size_t)node * HID + c] = selu_f(val);
}

// ---- fused layer-2: CSR gather (agg2 in registers) + W2 matmul + selu ----
__launch_bounds__(256)
__global__ void agg2h2_kernel(const int* __restrict__ rowptr, const int2* __restrict__ csr,
                              const float* __restrict__ h1, const float* __restrict__ dis,
                              const float* __restrict__ W2, const float* __restrict__ b2,
                              float* __restrict__ h2) {
    __shared__ float w2s[HID * HID];      // 16 KB
    for (int idx = threadIdx.x; idx < HID * HID; idx += 256) w2s[idx] = W2[idx];
    __syncthreads();

    int node = blockIdx.x * 4 + (threadIdx.x >> 6);
    int c = threadIdx.x & 63;
    int beg = rowptr[node], end = rowptr[node + 1];
    float acc = 0.f;
    int i = beg;
    for (; i + 3 < end; i += 4) {
        int2 a = csr[i];
        int2 b = csr[i + 1];
        int2 cc = csr[i + 2];
        int2 dd = csr[i + 3];
        acc = fmaf(h1[(size_t)a.x  * HID + c], __int_as_float(a.y),  acc);
        acc = fmaf(h1[(size_t)b.x  * HID + c], __int_as_float(b.y),  acc);
        acc = fmaf(h1[(size_t)cc.x * HID + c], __int_as_float(cc.y), acc);
        acc = fmaf(h1[(size_t)dd.x * HID + c], __int_as_float(dd.y), acc);
    }
    for (; i < end; ++i) {
        int2 a = csr[i];
        acc = fmaf(h1[(size_t)a.x * HID + c], __int_as_float(a.y), acc);
    }
    float ds = dis[node];
    size_t base = (size_t)node * HID + c;
    float inv = acc * ds + h1[base] * ds * ds;   // agg2 + h1*dis^2, channel c

    float o = b2[c];
    #pragma unroll
    for (int cc = 0; cc < HID; ++cc)
        o = fmaf(__shfl(inv, cc, 64), w2s[cc * HID + c], o);
    h2[base] = selu_f(o);
}

// ---- FC1: block = 512 thr x float4 = full 2048-wide row; KC contiguous rows ----
__launch_bounds__(512, 4)
__global__ void fc1_kernel(const float* __restrict__ h2, const float* __restrict__ Wf1,
                           float* __restrict__ partials) {
    __shared__ float hch[B_GR * KC];      // 8 KB, [b][kk]
    const int chunk = blockIdx.x;         // 0..NCHUNK-1
    const int k0 = chunk * KC;
    for (int idx = threadIdx.x; idx < B_GR * KC; idx += 512) {
        int b = idx >> 8;                 // KC = 256
        int kk = idx & (KC - 1);
        hch[idx] = h2[(size_t)b * KTOT + k0 + kk];
    }
    __syncthreads();
    float4 acc[B_GR];
    #pragma unroll
    for (int b = 0; b < B_GR; ++b) acc[b] = make_float4(0.f, 0.f, 0.f, 0.f);
    const int j = threadIdx.x * 4;
    const float* wp = Wf1 + (size_t)k0 * NJ + j;
    #pragma unroll 4
    for (int kk = 0; kk < KC; ++kk) {
        float4 w = *reinterpret_cast<const float4*>(wp);
        wp += NJ;
        #pragma unroll
        for (int b = 0; b < B_GR; ++b) {
            float hv = hch[b * KC + kk];
            acc[b].x = fmaf(w.x, hv, acc[b].x);
            acc[b].y = fmaf(w.y, hv, acc[b].y);
            acc[b].z = fmaf(w.z, hv, acc[b].z);
            acc[b].w = fmaf(w.w, hv, acc[b].w);
        }
    }
    float* pp = partials + (size_t)chunk * (B_GR * NJ) + j;
    #pragma unroll
    for (int b = 0; b < B_GR; ++b)
        *reinterpret_cast<float4*>(pp + (size_t)b * NJ) = acc[b];
}

// ---- reduce stage 1: 512 chunks -> 8 group-partials ----
__global__ void fc1_reduce1_kernel(const float* __restrict__ partials, float* __restrict__ tmp) {
    int idx = blockIdx.x * 256 + threadIdx.x;   // 0..16383
    int g = blockIdx.y;                         // 0..7  (64 chunks each)
    float s = 0.f;
    const float* p = partials + (size_t)(g * 64) * (B_GR * NJ) + idx;
    #pragma unroll 8
    for (int c = 0; c < 64; ++c) { s += *p; p += B_GR * NJ; }
    tmp[(size_t)g * (B_GR * NJ) + idx] = s;
}

// ---- FC2 (+ final reduce + FC1 bias & selu): out[b][m] ----
__global__ void fc2_kernel(const float* __restrict__ tmp, const float* __restrict__ bf1,
                           const float* __restrict__ Wf2, const float* __restrict__ bf2,
                           float* __restrict__ out) {
    int b = blockIdx.x;
    int t = threadIdx.x;  // 64
    float acc[MAXN];
    #pragma unroll
    for (int m = 0; m < MAXN; ++m) acc[m] = 0.f;
    for (int j = t; j < NJ; j += 64) {
        size_t o = (size_t)b * NJ + j;
        float s = 0.f;
        #pragma unroll
        for (int g = 0; g < 8; ++g) s += tmp[(size_t)g * (B_GR * NJ) + o];
        float zv = selu_f(s + bf1[j]);
        const float* wr = Wf2 + (size_t)j * MAXN;
        #pragma unroll
        for (int m = 0; m < MAXN; ++m) acc[m] = fmaf(zv, wr[m], acc[m]);
    }
    #pragma unroll
    for (int m = 0; m < MAXN; ++m) {
        float v = acc[m];
        for (int off = 32; off > 0; off >>= 1) v += __shfl_down(v, off, 64);
        if (t == 0) out[b * MAXN + m] = v + bf2[m];
    }
}

extern "C" void kernel_launch(void* const* d_in, const int* in_sizes, int n_in,
                              void* d_out, int out_size, void* d_ws, size_t ws_size,
                              hipStream_t stream) {
    const float* x    = (const float*)d_in[0];
    const int*   ei   = (const int*)d_in[1];      // int32 (JAX x64 disabled)
    const float* W1   = (const float*)d_in[2];
    const float* b1   = (const float*)d_in[3];
    const float* W2   = (const float*)d_in[4];
    const float* b2   = (const float*)d_in[5];
    const float* Wf1  = (const float*)d_in[6];
    const float* bf1  = (const float*)d_in[7];
    const float* Wf2  = (const float*)d_in[8];
    const float* bf2  = (const float*)d_in[9];
    float* out = (float*)d_out;

    const int* src = ei;
    const int* dst = ei + E_EDGES;

    char* ws = (char*)d_ws;
    int*   degi   = (int*)  (ws + OFF_DEGI);
    int*   cursor = (int*)  (ws + OFF_CURSOR);
    float* dis    = (float*)(ws + OFF_DIS);
    int*   rowptr = (int*)  (ws + OFF_ROWPTR);
    int2*  csr    = (int2*) (ws + OFF_CSR);
    float* h1     = (float*)(ws + OFF_H1);
    float* h2     = (float*)(ws + OFF_H2);
    float* tmp    = (float*)(ws + OFF_TMP);
    float* parts  = (float*)(ws + OFF_PART);

    // single contiguous zero: degi | cursor
    hipMemsetAsync(ws, 0, 0x20000, stream);

    deg_kernel <<<E_EDGES / 256, 256, 0, stream>>>(dst, degi);
    scan_kernel<<<1, 1024, 0, stream>>>(degi, rowptr, dis);
    scatter_kernel<<<E_EDGES / 256, 256, 0, stream>>>(src, dst, dis, rowptr, cursor, csr);
    gather1_kernel<<<N_TOT / 4, 256, 0, stream>>>(rowptr, csr, x, dis, W1, b1, h1);
    agg2h2_kernel<<<N_TOT / 4, 256, 0, stream>>>(rowptr, csr, h1, dis, W2, b2, h2);
    fc1_kernel <<<NCHUNK, 512, 0, stream>>>(h2, Wf1, parts);
    fc1_reduce1_kernel<<<dim3(64, 8), 256, 0, stream>>>(parts, tmp);
    fc2_kernel <<<B_GR, 64, 0, stream>>>(tmp, bf1, Wf2, bf2, out);
}

// Round 9
// 300.712 us; speedup vs baseline: 2.9831x; 1.2388x over previous
//
#include <hip/hip_runtime.h>
#include <cstdint>
#include <cstddef>

// ---------------- problem constants ----------------
#define E_EDGES     524288
#define N_TOT       16384      // total nodes (8 graphs x 2048)
#define HID         64
#define B_GR        8
#define KTOT        131072     // NPG*HID, FC1 inner dim
#define NJ          2048       // FC1 output width
#define MAXN        15
#define SLOTS       96         // fixed CSR capacity; deg ~ Binom(E,1/N): mean 32, sigma 5.7

// FC1 tiling: one block = full 2048-wide row (512 thr x float4), KC rows
#define KC          256
#define NCHUNK      512        // KTOT/KC

typedef float vf4 __attribute__((ext_vector_type(4)));   // native clang vector (nontemporal-ok)

// ---------------- workspace layout (bytes) ----------------
#define OFF_CURSOR  0x0u         // 64 KB (16384 int) -- the only memset
#define OFF_SLOTS   0x10000u     // 6.29 MB (16384 x 96 int)
#define OFF_H1      0x610000u    // 4 MB
#define OFF_H2      0xA10000u    // 4 MB
#define OFF_TMP     0xE10000u    // 512 KB (8 x 16384 f32)
#define OFF_PART    0xF00000u    // 33.55 MB (512 x 8 x 2048 f32)

__device__ __forceinline__ float selu_f(float x) {
    const float scale = 1.0507009873554805f;
    const float alpha = 1.6732632423543772f;
    return x > 0.0f ? scale * x : scale * alpha * expm1f(x);
}

// ---- build fixed-slot CSR: cursor RMW + int store; cursor ends as in-degree ----
__global__ void scatter_kernel(const int* __restrict__ src, const int* __restrict__ dst,
                               int* __restrict__ cursor, int* __restrict__ slots) {
    int e = blockIdx.x * 256 + threadIdx.x;
    if (e >= E_EDGES) return;
    int s = src[e], d = dst[e];
    int pos = atomicAdd(&cursor[d], 1);
    slots[d * SLOTS + pos] = s;
}

// ---- layer 1 fused: slot gather with on-the-fly x@W1 (linearity) ----
// h1[d][c] = selu( dis_d*sum_s dis_s*(x[s]@W1)_c + dis_d^2*(x[d]@W1)_c + b1[c] )
__launch_bounds__(256)
__global__ void gather1_kernel(const int* __restrict__ cursor, const int* __restrict__ slots,
                               const float* __restrict__ x,
                               const float* __restrict__ W1, const float* __restrict__ b1,
                               float* __restrict__ h1) {
    int node = blockIdx.x * 4 + (threadIdx.x >> 6);
    int c = threadIdx.x & 63;
    float w0 = W1[c], w1 = W1[64 + c], w2 = W1[128 + c], w3 = W1[192 + c];
    int deg = cursor[node];
    float ds = rsqrtf((float)(deg + 1));
    const int* sl = slots + node * SLOTS;
    float acc = 0.f;
    int i = 0;
    for (; i + 1 < deg; i += 2) {
        int sa = sl[i], sb = sl[i + 1];
        float da = rsqrtf((float)(cursor[sa] + 1));
        float db = rsqrtf((float)(cursor[sb] + 1));
        const float4 xa = *reinterpret_cast<const float4*>(x + (size_t)sa * 4);
        const float4 xb = *reinterpret_cast<const float4*>(x + (size_t)sb * 4);
        float xwa = fmaf(xa.x, w0, fmaf(xa.y, w1, fmaf(xa.z, w2, xa.w * w3)));
        float xwb = fmaf(xb.x, w0, fmaf(xb.y, w1, fmaf(xb.z, w2, xb.w * w3)));
        acc = fmaf(xwa, da, acc);
        acc = fmaf(xwb, db, acc);
    }
    if (i < deg) {
        int sa = sl[i];
        float da = rsqrtf((float)(cursor[sa] + 1));
        const float4 xa = *reinterpret_cast<const float4*>(x + (size_t)sa * 4);
        float xwa = fmaf(xa.x, w0, fmaf(xa.y, w1, fmaf(xa.z, w2, xa.w * w3)));
        acc = fmaf(xwa, da, acc);
    }
    const float4 xd = *reinterpret_cast<const float4*>(x + (size_t)node * 4);
    float xwd = fmaf(xd.x, w0, fmaf(xd.y, w1, fmaf(xd.z, w2, xd.w * w3)));
    float val = fmaf(acc, ds, xwd * ds * ds) + b1[c];
    h1[(size_t)node * HID + c] = selu_f(val);
}

// ---- fused layer-2: slot gather (agg2 in registers) + W2 matmul + selu ----
__launch_bounds__(256)
__global__ void agg2h2_kernel(const int* __restrict__ cursor, const int* __restrict__ slots,
                              const float* __restrict__ h1,
                              const float* __restrict__ W2, const float* __restrict__ b2,
                              float* __restrict__ h2) {
    __shared__ float w2s[HID * HID];      // 16 KB
    for (int idx = threadIdx.x; idx < HID * HID; idx += 256) w2s[idx] = W2[idx];
    __syncthreads();

    int node = blockIdx.x * 4 + (threadIdx.x >> 6);
    int c = threadIdx.x & 63;
    int deg = cursor[node];
    float ds = rsqrtf((float)(deg + 1));
    const int* sl = slots + node * SLOTS;
    float acc = 0.f;
    int i = 0;
    for (; i + 3 < deg; i += 4) {
        int sa = sl[i], sb = sl[i + 1], sc = sl[i + 2], sd = sl[i + 3];
        float da = rsqrtf((float)(cursor[sa] + 1));
        float db = rsqrtf((float)(cursor[sb] + 1));
        float dc = rsqrtf((float)(cursor[sc] + 1));
        float dd = rsqrtf((float)(cursor[sd] + 1));
        acc = fmaf(h1[(size_t)sa * HID + c], da, acc);
        acc = fmaf(h1[(size_t)sb * HID + c], db, acc);
        acc = fmaf(h1[(size_t)sc * HID + c], dc, acc);
        acc = fmaf(h1[(size_t)sd * HID + c], dd, acc);
    }
    for (; i < deg; ++i) {
        int sa = sl[i];
        float da = rsqrtf((float)(cursor[sa] + 1));
        acc = fmaf(h1[(size_t)sa * HID + c], da, acc);
    }
    size_t base = (size_t)node * HID + c;
    float inv = acc * ds + h1[base] * ds * ds;   // agg2 + h1*dis^2, channel c

    float o = b2[c];
    #pragma unroll
    for (int cc = 0; cc < HID; ++cc)
        o = fmaf(__shfl(inv, cc, 64), w2s[cc * HID + c], o);
    h2[base] = selu_f(o);
}

// ---- FC1: block = 512 thr x float4 = full 2048-wide row; KC contiguous rows.
// kk-tiles of 4: 4 nontemporal global vf4 + 8 ds_read_b128 + 128 FMA.
__launch_bounds__(512, 4)
__global__ void fc1_kernel(const float* __restrict__ h2, const float* __restrict__ Wf1,
                           float* __restrict__ partials) {
    __shared__ float hch[B_GR * KC];      // 8 KB, [b][kk]
    const int chunk = blockIdx.x;         // 0..NCHUNK-1
    const int k0 = chunk * KC;
    for (int idx = threadIdx.x; idx < B_GR * KC; idx += 512) {
        int b = idx >> 8;                 // KC = 256
        int kk = idx & (KC - 1);
        hch[idx] = h2[(size_t)b * KTOT + k0 + kk];
    }
    __syncthreads();
    vf4 acc[B_GR];
    #pragma unroll
    for (int b = 0; b < B_GR; ++b) acc[b] = (vf4)(0.f);
    const int j = threadIdx.x * 4;
    const float* wp = Wf1 + (size_t)k0 * NJ + j;
    #pragma unroll 2
    for (int kk4 = 0; kk4 < KC / 4; ++kk4) {
        vf4 w0 = __builtin_nontemporal_load(reinterpret_cast<const vf4*>(wp));
        vf4 w1 = __builtin_nontemporal_load(reinterpret_cast<const vf4*>(wp + NJ));
        vf4 w2 = __builtin_nontemporal_load(reinterpret_cast<const vf4*>(wp + 2 * NJ));
        vf4 w3 = __builtin_nontemporal_load(reinterpret_cast<const vf4*>(wp + 3 * NJ));
        wp += 4 * NJ;
        #pragma unroll
        for (int b = 0; b < B_GR; ++b) {
            const vf4 hv = *reinterpret_cast<const vf4*>(&hch[b * KC + kk4 * 4]);
            acc[b] += w0 * hv.x;
            acc[b] += w1 * hv.y;
            acc[b] += w2 * hv.z;
            acc[b] += w3 * hv.w;
        }
    }
    float* pp = partials + (size_t)chunk * (B_GR * NJ) + j;
    #pragma unroll
    for (int b = 0; b < B_GR; ++b)
        *reinterpret_cast<vf4*>(pp + (size_t)b * NJ) = acc[b];
}

// ---- reduce stage 1: 512 chunks -> 8 group-partials ----
__global__ void fc1_reduce1_kernel(const float* __restrict__ partials, float* __restrict__ tmp) {
    int idx = blockIdx.x * 256 + threadIdx.x;   // 0..16383
    int g = blockIdx.y;                         // 0..7  (64 chunks each)
    float s = 0.f;
    const float* p = partials + (size_t)(g * 64) * (B_GR * NJ) + idx;
    #pragma unroll 8
    for (int c = 0; c < 64; ++c) { s += *p; p += B_GR * NJ; }
    tmp[(size_t)g * (B_GR * NJ) + idx] = s;
}

// ---- FC2 (+ final reduce + FC1 bias & selu): out[b][m] ----
__global__ void fc2_kernel(const float* __restrict__ tmp, const float* __restrict__ bf1,
                           const float* __restrict__ Wf2, const float* __restrict__ bf2,
                           float* __restrict__ out) {
    int b = blockIdx.x;
    int t = threadIdx.x;  // 64
    float acc[MAXN];
    #pragma unroll
    for (int m = 0; m < MAXN; ++m) acc[m] = 0.f;
    for (int j = t; j < NJ; j += 64) {
        size_t o = (size_t)b * NJ + j;
        float s = 0.f;
        #pragma unroll
        for (int g = 0; g < 8; ++g) s += tmp[(size_t)g * (B_GR * NJ) + o];
        float zv = selu_f(s + bf1[j]);
        const float* wr = Wf2 + (size_t)j * MAXN;
        #pragma unroll
        for (int m = 0; m < MAXN; ++m) acc[m] = fmaf(zv, wr[m], acc[m]);
    }
    #pragma unroll
    for (int m = 0; m < MAXN; ++m) {
        float v = acc[m];
        for (int off = 32; off > 0; off >>= 1) v += __shfl_down(v, off, 64);
        if (t == 0) out[b * MAXN + m] = v + bf2[m];
    }
}

extern "C" void kernel_launch(void* const* d_in, const int* in_sizes, int n_in,
                              void* d_out, int out_size, void* d_ws, size_t ws_size,
                              hipStream_t stream) {
    const float* x    = (const float*)d_in[0];
    const int*   ei   = (const int*)d_in[1];      // int32 (JAX x64 disabled)
    const float* W1   = (const float*)d_in[2];
    const float* b1   = (const float*)d_in[3];
    const float* W2   = (const float*)d_in[4];
    const float* b2   = (const float*)d_in[5];
    const float* Wf1  = (const float*)d_in[6];
    const float* bf1  = (const float*)d_in[7];
    const float* Wf2  = (const float*)d_in[8];
    const float* bf2  = (const float*)d_in[9];
    float* out = (float*)d_out;

    const int* src = ei;
    const int* dst = ei + E_EDGES;

    char* ws = (char*)d_ws;
    int*   cursor = (int*)  (ws + OFF_CURSOR);
    int*   slots  = (int*)  (ws + OFF_SLOTS);
    float* h1     = (float*)(ws + OFF_H1);
    float* h2     = (float*)(ws + OFF_H2);
    float* tmp    = (float*)(ws + OFF_TMP);
    float* parts  = (float*)(ws + OFF_PART);

    (void)hipMemsetAsync(cursor, 0, N_TOT * sizeof(int), stream);

    scatter_kernel<<<E_EDGES / 256, 256, 0, stream>>>(src, dst, cursor, slots);
    gather1_kernel<<<N_TOT / 4, 256, 0, stream>>>(cursor, slots, x, W1, b1, h1);
    agg2h2_kernel<<<N_TOT / 4, 256, 0, stream>>>(cursor, slots, h1, W2, b2, h2);
    fc1_kernel <<<NCHUNK, 512, 0, stream>>>(h2, Wf1, parts);
    fc1_reduce1_kernel<<<dim3(64, 8), 256, 0, stream>>>(parts, tmp);
    fc2_kernel <<<B_GR, 64, 0, stream>>>(tmp, bf1, Wf2, bf2, out);
}

// Round 10
// 295.766 us; speedup vs baseline: 3.0330x; 1.0167x over previous
//
#include <hip/hip_runtime.h>
#include <cstdint>
#include <cstddef>

// ---------------- problem constants ----------------
#define E_EDGES     524288
#define N_TOT       16384      // total nodes (8 graphs x 2048)
#define HID         64
#define B_GR        8
#define KTOT        131072     // NPG*HID, FC1 inner dim
#define NJ          2048       // FC1 output width
#define MAXN        15
#define SLOTS       96         // fixed CSR capacity; deg ~ Binom(E,1/N): mean 32, sigma 5.7

// FC1 tiling: one block = full 2048-wide row (512 thr x float4), KC rows
#define KC          256
#define NCHUNK      512        // KTOT/KC

typedef float vf4 __attribute__((ext_vector_type(4)));   // native clang vector (nontemporal-ok)

// ---------------- workspace layout (bytes) ----------------
#define OFF_CURSOR  0x0u         // 64 KB (16384 int) -- the only memset
#define OFF_DIS     0x10000u     // 64 KB (16384 f32)
#define OFF_SLOTS   0x20000u     // 3.15 MB (16384 x 96 ushort)
#define OFF_H1      0x320000u    // 4 MB
#define OFF_H2      0x720000u    // 4 MB
#define OFF_TMP     0xB20000u    // 512 KB (8 x 16384 f32)
#define OFF_PART    0xBA0000u    // 33.55 MB (512 x 8 x 2048 f32)

__device__ __forceinline__ float selu_f(float x) {
    const float scale = 1.0507009873554805f;
    const float alpha = 1.6732632423543772f;
    return x > 0.0f ? scale * x : scale * alpha * expm1f(x);
}

// ---- build fixed-slot CSR (ushort cols): cursor RMW + store; cursor ends as in-degree ----
__global__ void scatter_kernel(const int* __restrict__ src, const int* __restrict__ dst,
                               int* __restrict__ cursor, unsigned short* __restrict__ slots) {
    int e = blockIdx.x * 256 + threadIdx.x;
    if (e >= E_EDGES) return;
    int s = src[e], d = dst[e];
    int pos = atomicAdd(&cursor[d], 1);
    slots[d * SLOTS + pos] = (unsigned short)s;
}

// ---- dis[i] = rsqrt(deg+1) ----
__global__ void dis_kernel(const int* __restrict__ cursor, float* __restrict__ dis) {
    int i = blockIdx.x * 256 + threadIdx.x;
    if (i < N_TOT) dis[i] = rsqrtf((float)(cursor[i] + 1));
}

// ---- layer 1 fused: slot gather with on-the-fly x@W1 (linearity) ----
// h1[d][c] = selu( dis_d*sum_s dis_s*(x[s]@W1)_c + dis_d^2*(x[d]@W1)_c + b1[c] )
__launch_bounds__(256)
__global__ void gather1_kernel(const int* __restrict__ cursor,
                               const unsigned short* __restrict__ slots,
                               const float* __restrict__ dis, const float* __restrict__ x,
                               const float* __restrict__ W1, const float* __restrict__ b1,
                               float* __restrict__ h1) {
    int node = blockIdx.x * 4 + (threadIdx.x >> 6);
    int c = threadIdx.x & 63;
    float w0 = W1[c], w1 = W1[64 + c], w2 = W1[128 + c], w3 = W1[192 + c];
    int deg = cursor[node];
    float ds = dis[node];
    const unsigned short* sl = slots + node * SLOTS;
    float acc = 0.f;
    int i = 0;
    for (; i + 1 < deg; i += 2) {
        int sa = sl[i], sb = sl[i + 1];
        float da = dis[sa], db = dis[sb];
        const float4 xa = *reinterpret_cast<const float4*>(x + (size_t)sa * 4);
        const float4 xb = *reinterpret_cast<const float4*>(x + (size_t)sb * 4);
        float xwa = fmaf(xa.x, w0, fmaf(xa.y, w1, fmaf(xa.z, w2, xa.w * w3)));
        float xwb = fmaf(xb.x, w0, fmaf(xb.y, w1, fmaf(xb.z, w2, xb.w * w3)));
        acc = fmaf(xwa, da, acc);
        acc = fmaf(xwb, db, acc);
    }
    if (i < deg) {
        int sa = sl[i];
        float da = dis[sa];
        const float4 xa = *reinterpret_cast<const float4*>(x + (size_t)sa * 4);
        float xwa = fmaf(xa.x, w0, fmaf(xa.y, w1, fmaf(xa.z, w2, xa.w * w3)));
        acc = fmaf(xwa, da, acc);
    }
    const float4 xd = *reinterpret_cast<const float4*>(x + (size_t)node * 4);
    float xwd = fmaf(xd.x, w0, fmaf(xd.y, w1, fmaf(xd.z, w2, xd.w * w3)));
    float val = fmaf(acc, ds, xwd * ds * ds) + b1[c];
    h1[(size_t)node * HID + c] = selu_f(val);
}

// ---- fused layer-2: slot gather (agg2 in registers) + W2 matmul + selu ----
__launch_bounds__(256)
__global__ void agg2h2_kernel(const int* __restrict__ cursor,
                              const unsigned short* __restrict__ slots,
                              const float* __restrict__ dis, const float* __restrict__ h1,
                              const float* __restrict__ W2, const float* __restrict__ b2,
                              float* __restrict__ h2) {
    __shared__ float w2s[HID * HID];      // 16 KB
    for (int idx = threadIdx.x; idx < HID * HID; idx += 256) w2s[idx] = W2[idx];
    __syncthreads();

    int node = blockIdx.x * 4 + (threadIdx.x >> 6);
    int c = threadIdx.x & 63;
    int deg = cursor[node];
    float ds = dis[node];
    const unsigned short* sl = slots + node * SLOTS;
    float acc = 0.f;
    int i = 0;
    for (; i + 3 < deg; i += 4) {
        int sa = sl[i], sb = sl[i + 1], sc = sl[i + 2], sd = sl[i + 3];
        float da = dis[sa], db = dis[sb], dc = dis[sc], dd = dis[sd];
        acc = fmaf(h1[(size_t)sa * HID + c], da, acc);
        acc = fmaf(h1[(size_t)sb * HID + c], db, acc);
        acc = fmaf(h1[(size_t)sc * HID + c], dc, acc);
        acc = fmaf(h1[(size_t)sd * HID + c], dd, acc);
    }
    for (; i < deg; ++i) {
        int sa = sl[i];
        acc = fmaf(h1[(size_t)sa * HID + c], dis[sa], acc);
    }
    size_t base = (size_t)node * HID + c;
    float inv = acc * ds + h1[base] * ds * ds;   // agg2 + h1*dis^2, channel c

    float o = b2[c];
    #pragma unroll
    for (int cc = 0; cc < HID; ++cc)
        o = fmaf(__shfl(inv, cc, 64), w2s[cc * HID + c], o);
    h2[base] = selu_f(o);
}

// ---- FC1: block = 512 thr x float4 = full 2048-wide row; KC contiguous rows.
// kk-tiles of 4, unroll 4 (16 nontemporal loads in flight).
__launch_bounds__(512, 4)
__global__ void fc1_kernel(const float* __restrict__ h2, const float* __restrict__ Wf1,
                           float* __restrict__ partials) {
    __shared__ float hch[B_GR * KC];      // 8 KB, [b][kk]
    const int chunk = blockIdx.x;         // 0..NCHUNK-1
    const int k0 = chunk * KC;
    for (int idx = threadIdx.x; idx < B_GR * KC; idx += 512) {
        int b = idx >> 8;                 // KC = 256
        int kk = idx & (KC - 1);
        hch[idx] = h2[(size_t)b * KTOT + k0 + kk];
    }
    __syncthreads();
    vf4 acc[B_GR];
    #pragma unroll
    for (int b = 0; b < B_GR; ++b) acc[b] = (vf4)(0.f);
    const int j = threadIdx.x * 4;
    const float* wp = Wf1 + (size_t)k0 * NJ + j;
    #pragma unroll 4
    for (int kk4 = 0; kk4 < KC / 4; ++kk4) {
        vf4 w0 = __builtin_nontemporal_load(reinterpret_cast<const vf4*>(wp));
        vf4 w1 = __builtin_nontemporal_load(reinterpret_cast<const vf4*>(wp + NJ));
        vf4 w2 = __builtin_nontemporal_load(reinterpret_cast<const vf4*>(wp + 2 * NJ));
        vf4 w3 = __builtin_nontemporal_load(reinterpret_cast<const vf4*>(wp + 3 * NJ));
        wp += 4 * NJ;
        #pragma unroll
        for (int b = 0; b < B_GR; ++b) {
            const vf4 hv = *reinterpret_cast<const vf4*>(&hch[b * KC + kk4 * 4]);
            acc[b] += w0 * hv.x;
            acc[b] += w1 * hv.y;
            acc[b] += w2 * hv.z;
            acc[b] += w3 * hv.w;
        }
    }
    float* pp = partials + (size_t)chunk * (B_GR * NJ) + j;
    #pragma unroll
    for (int b = 0; b < B_GR; ++b)
        *reinterpret_cast<vf4*>(pp + (size_t)b * NJ) = acc[b];
}

// ---- reduce stage 1: 512 chunks -> 8 group-partials ----
__global__ void fc1_reduce1_kernel(const float* __restrict__ partials, float* __restrict__ tmp) {
    int idx = blockIdx.x * 256 + threadIdx.x;   // 0..16383
    int g = blockIdx.y;                         // 0..7  (64 chunks each)
    float s = 0.f;
    const float* p = partials + (size_t)(g * 64) * (B_GR * NJ) + idx;
    #pragma unroll 8
    for (int c = 0; c < 64; ++c) { s += *p; p += B_GR * NJ; }
    tmp[(size_t)g * (B_GR * NJ) + idx] = s;
}

// ---- FC2 (+ final reduce + FC1 bias & selu): out[b][m] ----
__global__ void fc2_kernel(const float* __restrict__ tmp, const float* __restrict__ bf1,
                           const float* __restrict__ Wf2, const float* __restrict__ bf2,
                           float* __restrict__ out) {
    int b = blockIdx.x;
    int t = threadIdx.x;  // 64
    float acc[MAXN];
    #pragma unroll
    for (int m = 0; m < MAXN; ++m) acc[m] = 0.f;
    for (int j = t; j < NJ; j += 64) {
        size_t o = (size_t)b * NJ + j;
        float s = 0.f;
        #pragma unroll
        for (int g = 0; g < 8; ++g) s += tmp[(size_t)g * (B_GR * NJ) + o];
        float zv = selu_f(s + bf1[j]);
        const float* wr = Wf2 + (size_t)j * MAXN;
        #pragma unroll
        for (int m = 0; m < MAXN; ++m) acc[m] = fmaf(zv, wr[m], acc[m]);
    }
    #pragma unroll
    for (int m = 0; m < MAXN; ++m) {
        float v = acc[m];
        for (int off = 32; off > 0; off >>= 1) v += __shfl_down(v, off, 64);
        if (t == 0) out[b * MAXN + m] = v + bf2[m];
    }
}

extern "C" void kernel_launch(void* const* d_in, const int* in_sizes, int n_in,
                              void* d_out, int out_size, void* d_ws, size_t ws_size,
                              hipStream_t stream) {
    const float* x    = (const float*)d_in[0];
    const int*   ei   = (const int*)d_in[1];      // int32 (JAX x64 disabled)
    const float* W1   = (const float*)d_in[2];
    const float* b1   = (const float*)d_in[3];
    const float* W2   = (const float*)d_in[4];
    const float* b2   = (const float*)d_in[5];
    const float* Wf1  = (const float*)d_in[6];
    const float* bf1  = (const float*)d_in[7];
    const float* Wf2  = (const float*)d_in[8];
    const float* bf2  = (const float*)d_in[9];
    float* out = (float*)d_out;

    const int* src = ei;
    const int* dst = ei + E_EDGES;

    char* ws = (char*)d_ws;
    int*            cursor = (int*)            (ws + OFF_CURSOR);
    float*          dis    = (float*)          (ws + OFF_DIS);
    unsigned short* slots  = (unsigned short*) (ws + OFF_SLOTS);
    float*          h1     = (float*)          (ws + OFF_H1);
    float*          h2     = (float*)          (ws + OFF_H2);
    float*          tmp    = (float*)          (ws + OFF_TMP);
    float*          parts  = (float*)          (ws + OFF_PART);

    (void)hipMemsetAsync(cursor, 0, N_TOT * sizeof(int), stream);

    scatter_kernel<<<E_EDGES / 256, 256, 0, stream>>>(src, dst, cursor, slots);
    dis_kernel<<<N_TOT / 256, 256, 0, stream>>>(cursor, dis);
    gather1_kernel<<<N_TOT / 4, 256, 0, stream>>>(cursor, slots, dis, x, W1, b1, h1);
    agg2h2_kernel<<<N_TOT / 4, 256, 0, stream>>>(cursor, slots, dis, h1, W2, b2, h2);
    fc1_kernel <<<NCHUNK, 512, 0, stream>>>(h2, Wf1, parts);
    fc1_reduce1_kernel<<<dim3(64, 8), 256, 0, stream>>>(parts, tmp);
    fc2_kernel <<<B_GR, 64, 0, stream>>>(tmp, bf1, Wf2, bf2, out);
}